// Round 2
// baseline (3805.576 us; speedup 1.0000x reference)
//
#include <hip/hip_runtime.h>
#include <math.h>

#define B_   4
#define S_   256
#define SK_  512
#define D_   1024
#define NH_  16
#define NKV_ 4
#define HD_  64
#define DE_  4096
#define NE_  8

// ---------------- layernorm (one block per row, D=1024, 256 thr) ----------------
__global__ __launch_bounds__(256) void ln_kernel(const float* __restrict__ x,
                                                 const float* __restrict__ g,
                                                 const float* __restrict__ be,
                                                 float* __restrict__ y) {
  int row = blockIdx.x, tid = threadIdx.x;
  const float4 v = ((const float4*)(x + (size_t)row * D_))[tid];
  float s  = v.x + v.y + v.z + v.w;
  float s2 = v.x*v.x + v.y*v.y + v.z*v.z + v.w*v.w;
  __shared__ float r1[256], r2[256];
  r1[tid] = s; r2[tid] = s2; __syncthreads();
  for (int off = 128; off > 0; off >>= 1) {
    if (tid < off) { r1[tid] += r1[tid+off]; r2[tid] += r2[tid+off]; }
    __syncthreads();
  }
  float mean = r1[0] * (1.0f / D_);
  float var  = r2[0] * (1.0f / D_) - mean * mean;
  float inv  = rsqrtf(var + 1e-5f);
  float* yr = y + (size_t)row * D_;
  int c = tid * 4;
  yr[c]   = (v.x - mean) * inv * g[c]   + be[c];
  yr[c+1] = (v.y - mean) * inv * g[c+1] + be[c+1];
  yr[c+2] = (v.z - mean) * inv * g[c+2] + be[c+2];
  yr[c+3] = (v.w - mean) * inv * g[c+3] + be[c+3];
}

// ---------------- generic GEMM: C = scale*(A@W + bias) [+ resid] ----------------
// A fp32 [M,K], W fp32 [K,N], bias fp32 [N], C fp32 [M,N]. 64x64 tile, BK=16, 4x4/thread.
__global__ __launch_bounds__(256) void gemm_bias(const float* __restrict__ A,
                                                 const float* __restrict__ W,
                                                 const float* __restrict__ bias,
                                                 const float* __restrict__ resid,
                                                 float* __restrict__ C,
                                                 float scale, int M, int N, int K) {
  __shared__ float As[16][64];
  __shared__ float Ws[16][64];
  int bm = blockIdx.y * 64, bn = blockIdx.x * 64;
  int tid = threadIdx.x;
  int tx = tid & 15, ty = tid >> 4;
  int ar = tid >> 2, ac4 = (tid & 3) * 4;
  int wr = tid >> 4, wc = (tid & 15) * 4;
  float acc[4][4] = {};
  for (int k0 = 0; k0 < K; k0 += 16) {
    float4 av = *(const float4*)(A + (size_t)(bm + ar) * K + k0 + ac4);
    As[ac4+0][ar] = av.x; As[ac4+1][ar] = av.y; As[ac4+2][ar] = av.z; As[ac4+3][ar] = av.w;
    float4 wv = *(const float4*)(W + (size_t)(k0 + wr) * N + bn + wc);
    Ws[wr][wc+0] = wv.x; Ws[wr][wc+1] = wv.y;
    Ws[wr][wc+2] = wv.z; Ws[wr][wc+3] = wv.w;
    __syncthreads();
#pragma unroll
    for (int kk = 0; kk < 16; ++kk) {
      float a0[4], w0[4];
#pragma unroll
      for (int i = 0; i < 4; ++i) a0[i] = As[kk][ty*4 + i];
#pragma unroll
      for (int j = 0; j < 4; ++j) w0[j] = Ws[kk][tx*4 + j];
#pragma unroll
      for (int i = 0; i < 4; ++i)
#pragma unroll
        for (int j = 0; j < 4; ++j) acc[i][j] += a0[i] * w0[j];
    }
    __syncthreads();
  }
#pragma unroll
  for (int i = 0; i < 4; ++i) {
    int m = bm + ty*4 + i;
#pragma unroll
    for (int j = 0; j < 4; ++j) {
      int n = bn + tx*4 + j;
      float v = (acc[i][j] + bias[n]) * scale;
      if (resid) v += resid[(size_t)m * N + n];
      C[(size_t)m * N + n] = v;
    }
  }
}

// ---------------- MoE gate: H = gelu(A@W1) * (A@W3), skip if coef==0 ----------------
__global__ __launch_bounds__(256) void moe_gate(const float* __restrict__ A,
                                                const float* __restrict__ W1,
                                                const float* __restrict__ W3,
                                                float* __restrict__ H,
                                                const float* __restrict__ coef, int e) {
  int bm = blockIdx.y * 64, bn = blockIdx.x * 64;
  int b = bm / S_;
  if (coef[e * B_ + b] == 0.0f) return;
  const int K = D_, N = DE_;
  __shared__ float As[16][64];
  __shared__ float W1s[16][64];
  __shared__ float W3s[16][64];
  int tid = threadIdx.x;
  int tx = tid & 15, ty = tid >> 4;
  int ar = tid >> 2, ac4 = (tid & 3) * 4;
  int wr = tid >> 4, wc = (tid & 15) * 4;
  float acc1[4][4] = {};
  float acc3[4][4] = {};
  for (int k0 = 0; k0 < K; k0 += 16) {
    float4 av = *(const float4*)(A + (size_t)(bm + ar) * K + k0 + ac4);
    As[ac4+0][ar] = av.x; As[ac4+1][ar] = av.y; As[ac4+2][ar] = av.z; As[ac4+3][ar] = av.w;
    float4 w1v = *(const float4*)(W1 + (size_t)(k0 + wr) * N + bn + wc);
    W1s[wr][wc+0] = w1v.x; W1s[wr][wc+1] = w1v.y;
    W1s[wr][wc+2] = w1v.z; W1s[wr][wc+3] = w1v.w;
    float4 w3v = *(const float4*)(W3 + (size_t)(k0 + wr) * N + bn + wc);
    W3s[wr][wc+0] = w3v.x; W3s[wr][wc+1] = w3v.y;
    W3s[wr][wc+2] = w3v.z; W3s[wr][wc+3] = w3v.w;
    __syncthreads();
#pragma unroll
    for (int kk = 0; kk < 16; ++kk) {
      float a0[4], w1r[4], w3r[4];
#pragma unroll
      for (int i = 0; i < 4; ++i) a0[i] = As[kk][ty*4 + i];
#pragma unroll
      for (int j = 0; j < 4; ++j) { w1r[j] = W1s[kk][tx*4 + j]; w3r[j] = W3s[kk][tx*4 + j]; }
#pragma unroll
      for (int i = 0; i < 4; ++i)
#pragma unroll
        for (int j = 0; j < 4; ++j) {
          acc1[i][j] += a0[i] * w1r[j];
          acc3[i][j] += a0[i] * w3r[j];
        }
    }
    __syncthreads();
  }
#pragma unroll
  for (int i = 0; i < 4; ++i) {
    int m = bm + ty*4 + i;
#pragma unroll
    for (int j = 0; j < 4; ++j) {
      int n = bn + tx*4 + j;
      float gg = acc1[i][j];
      float gelu = 0.5f * gg * (1.0f + erff(gg * 0.70710678118654752f));
      H[(size_t)m * N + n] = gelu * acc3[i][j];
    }
  }
}

// ---------------- MoE down: resid += coef * (H @ W2), skip if coef==0 ----------------
__global__ __launch_bounds__(256) void moe_down(const float* __restrict__ H,
                                                const float* __restrict__ W2,
                                                float* __restrict__ resid,
                                                const float* __restrict__ coef, int e) {
  int bm = blockIdx.y * 64, bn = blockIdx.x * 64;
  int b = bm / S_;
  float cf = coef[e * B_ + b];
  if (cf == 0.0f) return;
  const int K = DE_, N = D_;
  __shared__ float As[16][64];
  __shared__ float Ws[16][64];
  int tid = threadIdx.x;
  int tx = tid & 15, ty = tid >> 4;
  int ar = tid >> 2, ac4 = (tid & 3) * 4;
  int wr = tid >> 4, wc = (tid & 15) * 4;
  float acc[4][4] = {};
  for (int k0 = 0; k0 < K; k0 += 16) {
    float4 av = *(const float4*)(H + (size_t)(bm + ar) * K + k0 + ac4);
    As[ac4+0][ar] = av.x; As[ac4+1][ar] = av.y; As[ac4+2][ar] = av.z; As[ac4+3][ar] = av.w;
    float4 wv = *(const float4*)(W2 + (size_t)(k0 + wr) * N + bn + wc);
    Ws[wr][wc+0] = wv.x; Ws[wr][wc+1] = wv.y;
    Ws[wr][wc+2] = wv.z; Ws[wr][wc+3] = wv.w;
    __syncthreads();
#pragma unroll
    for (int kk = 0; kk < 16; ++kk) {
      float a0[4], w0[4];
#pragma unroll
      for (int i = 0; i < 4; ++i) a0[i] = As[kk][ty*4 + i];
#pragma unroll
      for (int j = 0; j < 4; ++j) w0[j] = Ws[kk][tx*4 + j];
#pragma unroll
      for (int i = 0; i < 4; ++i)
#pragma unroll
        for (int j = 0; j < 4; ++j) acc[i][j] += a0[i] * w0[j];
    }
    __syncthreads();
  }
#pragma unroll
  for (int i = 0; i < 4; ++i) {
    int m = bm + ty*4 + i;
#pragma unroll
    for (int j = 0; j < 4; ++j) {
      int n = bn + tx*4 + j;
      resid[(size_t)m * N + n] += cf * acc[i][j];
    }
  }
}

// ---------------- attention: one block per (b, h, q) ----------------
// q [B*S, D] (head h at col h*64), k/v [B*SKV, NKV*64], mask fp32 [B,1,S,SKV]
__global__ __launch_bounds__(256) void attn_kernel(const float* __restrict__ qb,
                                                   const float* __restrict__ kb,
                                                   const float* __restrict__ vb,
                                                   const float* __restrict__ mask,
                                                   float* __restrict__ ob, int SKV) {
  int qi = blockIdx.x, h = blockIdx.y, b = blockIdx.z;
  int kvh = h >> 2;   // NH/NKV = 4
  __shared__ float qs[64];
  __shared__ float sc[SK_];
  __shared__ float red[256];
  int tid = threadIdx.x;
  if (tid < 64) qs[tid] = qb[((size_t)(b*S_ + qi)) * D_ + h*HD_ + tid];
  __syncthreads();
  for (int k = tid; k < SKV; k += 256) {
    const float* kp = kb + ((size_t)(b*SKV + k)) * (NKV_*HD_) + kvh*HD_;
    float s = 0.f;
#pragma unroll
    for (int d = 0; d < HD_; ++d) s += qs[d] * kp[d];
    s += mask[((size_t)b*S_ + qi) * SKV + k];
    sc[k] = s;
  }
  __syncthreads();
  float lm = -1e30f;
  for (int k = tid; k < SKV; k += 256) lm = fmaxf(lm, sc[k]);
  red[tid] = lm; __syncthreads();
  for (int off = 128; off > 0; off >>= 1) {
    if (tid < off) red[tid] = fmaxf(red[tid], red[tid+off]);
    __syncthreads();
  }
  float mx = red[0]; __syncthreads();
  float ls = 0.f;
  for (int k = tid; k < SKV; k += 256) { float e_ = expf(sc[k] - mx); sc[k] = e_; ls += e_; }
  red[tid] = ls; __syncthreads();
  for (int off = 128; off > 0; off >>= 1) {
    if (tid < off) red[tid] += red[tid+off];
    __syncthreads();
  }
  float inv = 1.0f / red[0];
  __syncthreads();
  int d = tid & 63, sl = tid >> 6;
  float pa = 0.f;
  for (int k = sl; k < SKV; k += 4)
    pa += sc[k] * vb[((size_t)(b*SKV + k)) * (NKV_*HD_) + kvh*HD_ + d];
  red[tid] = pa * inv;
  __syncthreads();
  if (sl == 0)
    ob[((size_t)(b*S_ + qi)) * D_ + h*HD_ + d] = red[d] + red[64+d] + red[128+d] + red[192+d];
}

// ---------------- MoE routing coefficients ----------------
__global__ void coef_kernel(const int* __restrict__ langs, float* __restrict__ coef) {
  int t = threadIdx.x;
  if (t < NE_ * B_) {
    int e = t / B_, b = t % B_;
    int l0 = langs[b*2], l1 = langs[b*2 + 1];
    int counts = (l0 > 3) + (l1 > 3);
    float rw = (counts == 0) ? 1.0f : 1.0f / (float)counts;
    int code = 4 + e;
    bool m = (l0 == code) || (l1 == code);
    coef[e * B_ + b] = m ? rw : 0.0f;
  }
}

extern "C" void kernel_launch(void* const* d_in, const int* in_sizes, int n_in,
                              void* d_out, int out_size, void* d_ws, size_t ws_size,
                              hipStream_t stream) {
  const float* hidden = (const float*)d_in[0];
  const float* enc    = (const float*)d_in[1];
  const float* amask  = (const float*)d_in[2];
  const float* emask  = (const float*)d_in[3];
  const int*   langs  = (const int*)d_in[4];
  const float* ln1g = (const float*)d_in[5];
  const float* ln1b = (const float*)d_in[6];
  const float* saqw = (const float*)d_in[7];
  const float* saqb = (const float*)d_in[8];
  const float* sakw = (const float*)d_in[9];
  const float* sakb = (const float*)d_in[10];
  const float* savw = (const float*)d_in[11];
  const float* savb = (const float*)d_in[12];
  const float* saow = (const float*)d_in[13];
  const float* saob = (const float*)d_in[14];
  const float* ln2g = (const float*)d_in[15];
  const float* ln2b = (const float*)d_in[16];
  const float* caqw = (const float*)d_in[17];
  const float* caqb = (const float*)d_in[18];
  const float* cakw = (const float*)d_in[19];
  const float* cakb = (const float*)d_in[20];
  const float* cavw = (const float*)d_in[21];
  const float* cavb = (const float*)d_in[22];
  const float* caow = (const float*)d_in[23];
  const float* caob = (const float*)d_in[24];
  const float* ln3g = (const float*)d_in[25];
  const float* ln3b = (const float*)d_in[26];
  const float* w1   = (const float*)d_in[27];
  const float* w2   = (const float*)d_in[28];
  const float* w3   = (const float*)d_in[29];

  float* resid = (float*)d_out;                 // residual stream lives in d_out (fp32, B*S*D)

  float* ws = (float*)d_ws;
  float* xln   = ws;  ws += B_*S_*D_;           // 1,048,576
  float* qbuf  = ws;  ws += B_*S_*D_;           // 1,048,576
  float* kbuf  = ws;  ws += B_*SK_*NKV_*HD_;    //   524,288
  float* vbuf  = ws;  ws += B_*SK_*NKV_*HD_;    //   524,288
  float* abuf  = ws;  ws += B_*S_*D_;           // 1,048,576
  float* Hbuf  = ws;  ws += B_*S_*DE_;          // 4,194,304
  float* coef  = ws;  ws += 64;                 // total ~33.6 MB

  dim3 blk(256);
  const int M = B_ * S_;       // 1024
  const int MK = B_ * SK_;     // 2048
  const float qscale = 0.125f; // HD^-0.5

  // ---- self attention ----
  ln_kernel<<<M, blk, 0, stream>>>(hidden, ln1g, ln1b, xln);
  gemm_bias<<<dim3(D_/64, M/64), blk, 0, stream>>>(xln, saqw, saqb, nullptr, qbuf, qscale, M, D_, D_);
  gemm_bias<<<dim3((NKV_*HD_)/64, M/64), blk, 0, stream>>>(xln, sakw, sakb, nullptr, kbuf, 1.0f, M, NKV_*HD_, D_);
  gemm_bias<<<dim3((NKV_*HD_)/64, M/64), blk, 0, stream>>>(xln, savw, savb, nullptr, vbuf, 1.0f, M, NKV_*HD_, D_);
  attn_kernel<<<dim3(S_, NH_, B_), blk, 0, stream>>>(qbuf, kbuf, vbuf, amask, abuf, S_);
  // resid (d_out) = abuf@ow + ob + hidden   (fully overwrites d_out before any read of it)
  gemm_bias<<<dim3(D_/64, M/64), blk, 0, stream>>>(abuf, saow, saob, hidden, resid, 1.0f, M, D_, D_);

  // ---- cross attention ----
  ln_kernel<<<M, blk, 0, stream>>>(resid, ln2g, ln2b, xln);
  gemm_bias<<<dim3(D_/64, M/64), blk, 0, stream>>>(xln, caqw, caqb, nullptr, qbuf, qscale, M, D_, D_);
  gemm_bias<<<dim3((NKV_*HD_)/64, MK/64), blk, 0, stream>>>(enc, cakw, cakb, nullptr, kbuf, 1.0f, MK, NKV_*HD_, D_);
  gemm_bias<<<dim3((NKV_*HD_)/64, MK/64), blk, 0, stream>>>(enc, cavw, cavb, nullptr, vbuf, 1.0f, MK, NKV_*HD_, D_);
  attn_kernel<<<dim3(S_, NH_, B_), blk, 0, stream>>>(qbuf, kbuf, vbuf, emask, abuf, SK_);
  gemm_bias<<<dim3(D_/64, M/64), blk, 0, stream>>>(abuf, caow, caob, resid, resid, 1.0f, M, D_, D_);

  // ---- MoE ----
  ln_kernel<<<M, blk, 0, stream>>>(resid, ln3g, ln3b, xln);
  coef_kernel<<<1, 64, 0, stream>>>(langs, coef);
  for (int e = 0; e < NE_; ++e) {
    moe_gate<<<dim3(DE_/64, M/64), blk, 0, stream>>>(xln,
        w1 + (size_t)e * D_ * DE_, w3 + (size_t)e * D_ * DE_, Hbuf, coef, e);
    moe_down<<<dim3(D_/64, M/64), blk, 0, stream>>>(Hbuf,
        w2 + (size_t)e * DE_ * D_, resid, coef, e);
  }
}

// Round 3
// 2500.548 us; speedup vs baseline: 1.5219x; 1.5219x over previous
//
#include <hip/hip_runtime.h>
#include <math.h>

#define B_   4
#define S_   256
#define SK_  512
#define D_   1024
#define NH_  16
#define NKV_ 4
#define HD_  64
#define DE_  4096
#define NE_  8

// ---------------- layernorm (one block per row, D=1024, 256 thr) ----------------
__global__ __launch_bounds__(256) void ln_kernel(const float* __restrict__ x,
                                                 const float* __restrict__ g,
                                                 const float* __restrict__ be,
                                                 float* __restrict__ y) {
  int row = blockIdx.x, tid = threadIdx.x;
  const float4 v = ((const float4*)(x + (size_t)row * D_))[tid];
  float s  = v.x + v.y + v.z + v.w;
  float s2 = v.x*v.x + v.y*v.y + v.z*v.z + v.w*v.w;
  __shared__ float r1[256], r2[256];
  r1[tid] = s; r2[tid] = s2; __syncthreads();
  for (int off = 128; off > 0; off >>= 1) {
    if (tid < off) { r1[tid] += r1[tid+off]; r2[tid] += r2[tid+off]; }
    __syncthreads();
  }
  float mean = r1[0] * (1.0f / D_);
  float var  = r2[0] * (1.0f / D_) - mean * mean;
  float inv  = rsqrtf(var + 1e-5f);
  float* yr = y + (size_t)row * D_;
  int c = tid * 4;
  yr[c]   = (v.x - mean) * inv * g[c]   + be[c];
  yr[c+1] = (v.y - mean) * inv * g[c+1] + be[c+1];
  yr[c+2] = (v.z - mean) * inv * g[c+2] + be[c+2];
  yr[c+3] = (v.w - mean) * inv * g[c+3] + be[c+3];
}

// ---------------- generic GEMM: C = scale*(A@W + bias) [+ resid] ----------------
__global__ __launch_bounds__(256) void gemm_bias(const float* __restrict__ A,
                                                 const float* __restrict__ W,
                                                 const float* __restrict__ bias,
                                                 const float* __restrict__ resid,
                                                 float* __restrict__ C,
                                                 float scale, int M, int N, int K) {
  __shared__ float As[16][64];
  __shared__ float Ws[16][64];
  int bm = blockIdx.y * 64, bn = blockIdx.x * 64;
  int tid = threadIdx.x;
  int tx = tid & 15, ty = tid >> 4;
  int ar = tid >> 2, ac4 = (tid & 3) * 4;
  int wr = tid >> 4, wc = (tid & 15) * 4;
  float acc[4][4] = {};
  for (int k0 = 0; k0 < K; k0 += 16) {
    float4 av = *(const float4*)(A + (size_t)(bm + ar) * K + k0 + ac4);
    As[ac4+0][ar] = av.x; As[ac4+1][ar] = av.y; As[ac4+2][ar] = av.z; As[ac4+3][ar] = av.w;
    float4 wv = *(const float4*)(W + (size_t)(k0 + wr) * N + bn + wc);
    Ws[wr][wc+0] = wv.x; Ws[wr][wc+1] = wv.y;
    Ws[wr][wc+2] = wv.z; Ws[wr][wc+3] = wv.w;
    __syncthreads();
#pragma unroll
    for (int kk = 0; kk < 16; ++kk) {
      float a0[4], w0[4];
#pragma unroll
      for (int i = 0; i < 4; ++i) a0[i] = As[kk][ty*4 + i];
#pragma unroll
      for (int j = 0; j < 4; ++j) w0[j] = Ws[kk][tx*4 + j];
#pragma unroll
      for (int i = 0; i < 4; ++i)
#pragma unroll
        for (int j = 0; j < 4; ++j) acc[i][j] += a0[i] * w0[j];
    }
    __syncthreads();
  }
#pragma unroll
  for (int i = 0; i < 4; ++i) {
    int m = bm + ty*4 + i;
#pragma unroll
    for (int j = 0; j < 4; ++j) {
      int n = bn + tx*4 + j;
      float v = (acc[i][j] + bias[n]) * scale;
      if (resid) v += resid[(size_t)m * N + n];
      C[(size_t)m * N + n] = v;
    }
  }
}

// ---------------- QK^T + mask:  sc[(zb*NH+h), qi, k] = q . k + mask ----------------
// qbuf [B*S, D] (head h cols h*64..), kbuf [B*SKV, NKV*64], mask [B,1,S,SKV]
__global__ __launch_bounds__(256) void qk_kernel(const float* __restrict__ qb,
                                                 const float* __restrict__ kb,
                                                 const float* __restrict__ mask,
                                                 float* __restrict__ sc,
                                                 int b0, int SKV) {
  int z = blockIdx.z;
  int zb = z >> 4, h = z & 15;
  int b = b0 + zb;
  int kvh = h >> 2;
  int bq = blockIdx.y * 64, bk = blockIdx.x * 64;
  __shared__ float As[16][64];   // [d][qrow]
  __shared__ float Bs[16][64];   // [d][kcol]
  int tid = threadIdx.x;
  int tx = tid & 15, ty = tid >> 4;
  int ar = tid >> 2, ac4 = (tid & 3) * 4;   // ar: row/col 0..63, ac4: d-offset
  float acc[4][4] = {};
  for (int k0 = 0; k0 < HD_; k0 += 16) {
    float4 av = *(const float4*)(qb + (size_t)(b*S_ + bq + ar) * D_ + h*HD_ + k0 + ac4);
    As[ac4+0][ar] = av.x; As[ac4+1][ar] = av.y; As[ac4+2][ar] = av.z; As[ac4+3][ar] = av.w;
    float4 bv = *(const float4*)(kb + (size_t)(b*SKV + bk + ar) * (NKV_*HD_) + kvh*HD_ + k0 + ac4);
    Bs[ac4+0][ar] = bv.x; Bs[ac4+1][ar] = bv.y; Bs[ac4+2][ar] = bv.z; Bs[ac4+3][ar] = bv.w;
    __syncthreads();
#pragma unroll
    for (int kk = 0; kk < 16; ++kk) {
      float a0[4], w0[4];
#pragma unroll
      for (int i = 0; i < 4; ++i) a0[i] = As[kk][ty*4 + i];
#pragma unroll
      for (int j = 0; j < 4; ++j) w0[j] = Bs[kk][tx*4 + j];
#pragma unroll
      for (int i = 0; i < 4; ++i)
#pragma unroll
        for (int j = 0; j < 4; ++j) acc[i][j] += a0[i] * w0[j];
    }
    __syncthreads();
  }
#pragma unroll
  for (int i = 0; i < 4; ++i) {
    int qi = bq + ty*4 + i;
#pragma unroll
    for (int j = 0; j < 4; ++j) {
      int kc = bk + tx*4 + j;
      sc[((size_t)(zb*NH_ + h) * S_ + qi) * SKV + kc] =
          acc[i][j] + mask[((size_t)(b*S_ + qi)) * SKV + kc];
    }
  }
}

// ---------------- row softmax over sc, one wave per row ----------------
__global__ __launch_bounds__(256) void softmax_kernel(float* __restrict__ sc, int SKV, int nrows) {
  int row = blockIdx.x * 4 + (threadIdx.x >> 6);
  int lane = threadIdx.x & 63;
  if (row >= nrows) return;
  float* rp = sc + (size_t)row * SKV;
  float4 v[2];
  int nc = SKV >> 8;           // 1 (SKV=256) or 2 (SKV=512) float4 chunks per lane
  float mx = -1e30f;
#pragma unroll
  for (int c = 0; c < 2; ++c) {
    if (c < nc) {
      v[c] = *(float4*)(rp + c*256 + lane*4);
      mx = fmaxf(mx, fmaxf(fmaxf(v[c].x, v[c].y), fmaxf(v[c].z, v[c].w)));
    }
  }
#pragma unroll
  for (int m = 32; m > 0; m >>= 1) mx = fmaxf(mx, __shfl_xor(mx, m, 64));
  float ls = 0.f;
#pragma unroll
  for (int c = 0; c < 2; ++c) {
    if (c < nc) {
      v[c].x = __expf(v[c].x - mx); v[c].y = __expf(v[c].y - mx);
      v[c].z = __expf(v[c].z - mx); v[c].w = __expf(v[c].w - mx);
      ls += v[c].x + v[c].y + v[c].z + v[c].w;
    }
  }
#pragma unroll
  for (int m = 32; m > 0; m >>= 1) ls += __shfl_xor(ls, m, 64);
  float inv = 1.0f / ls;
#pragma unroll
  for (int c = 0; c < 2; ++c) {
    if (c < nc) {
      v[c].x *= inv; v[c].y *= inv; v[c].z *= inv; v[c].w *= inv;
      *(float4*)(rp + c*256 + lane*4) = v[c];
    }
  }
}

// ---------------- P @ V:  abuf[b, qi, h*64+d] = sum_k p * v ----------------
__global__ __launch_bounds__(256) void pv_kernel(const float* __restrict__ sc,
                                                 const float* __restrict__ vb,
                                                 float* __restrict__ ob,
                                                 int b0, int SKV) {
  int z = blockIdx.y;
  int zb = z >> 4, h = z & 15;
  int b = b0 + zb;
  int kvh = h >> 2;
  int bq = blockIdx.x * 64;
  __shared__ float As[16][64];   // [k][qrow]
  __shared__ float Bs[16][64];   // [k][d]
  int tid = threadIdx.x;
  int tx = tid & 15, ty = tid >> 4;
  int ar = tid >> 2, ac4 = (tid & 3) * 4;
  int wr = tid >> 4, wc = (tid & 15) * 4;
  float acc[4][4] = {};
  for (int k0 = 0; k0 < SKV; k0 += 16) {
    float4 av = *(const float4*)(sc + ((size_t)(zb*NH_ + h) * S_ + bq + ar) * SKV + k0 + ac4);
    As[ac4+0][ar] = av.x; As[ac4+1][ar] = av.y; As[ac4+2][ar] = av.z; As[ac4+3][ar] = av.w;
    float4 bv = *(const float4*)(vb + (size_t)(b*SKV + k0 + wr) * (NKV_*HD_) + kvh*HD_ + wc);
    Bs[wr][wc+0] = bv.x; Bs[wr][wc+1] = bv.y;
    Bs[wr][wc+2] = bv.z; Bs[wr][wc+3] = bv.w;
    __syncthreads();
#pragma unroll
    for (int kk = 0; kk < 16; ++kk) {
      float a0[4], w0[4];
#pragma unroll
      for (int i = 0; i < 4; ++i) a0[i] = As[kk][ty*4 + i];
#pragma unroll
      for (int j = 0; j < 4; ++j) w0[j] = Bs[kk][tx*4 + j];
#pragma unroll
      for (int i = 0; i < 4; ++i)
#pragma unroll
        for (int j = 0; j < 4; ++j) acc[i][j] += a0[i] * w0[j];
    }
    __syncthreads();
  }
#pragma unroll
  for (int i = 0; i < 4; ++i) {
    int qi = bq + ty*4 + i;
#pragma unroll
    for (int j = 0; j < 4; ++j) {
      int d = tx*4 + j;
      ob[(size_t)(b*S_ + qi) * D_ + h*HD_ + d] = acc[i][j];
    }
  }
}

// ---------------- MoE gate: H = gelu(A@W1) * (A@W3), skip if coef==0 ----------------
__global__ __launch_bounds__(256) void moe_gate(const float* __restrict__ A,
                                                const float* __restrict__ W1,
                                                const float* __restrict__ W3,
                                                float* __restrict__ H,
                                                const float* __restrict__ coef, int e) {
  int bm = blockIdx.y * 64, bn = blockIdx.x * 64;
  int b = bm / S_;
  if (coef[e * B_ + b] == 0.0f) return;
  const int K = D_, N = DE_;
  __shared__ float As[16][64];
  __shared__ float W1s[16][64];
  __shared__ float W3s[16][64];
  int tid = threadIdx.x;
  int tx = tid & 15, ty = tid >> 4;
  int ar = tid >> 2, ac4 = (tid & 3) * 4;
  int wr = tid >> 4, wc = (tid & 15) * 4;
  float acc1[4][4] = {};
  float acc3[4][4] = {};
  for (int k0 = 0; k0 < K; k0 += 16) {
    float4 av = *(const float4*)(A + (size_t)(bm + ar) * K + k0 + ac4);
    As[ac4+0][ar] = av.x; As[ac4+1][ar] = av.y; As[ac4+2][ar] = av.z; As[ac4+3][ar] = av.w;
    float4 w1v = *(const float4*)(W1 + (size_t)(k0 + wr) * N + bn + wc);
    W1s[wr][wc+0] = w1v.x; W1s[wr][wc+1] = w1v.y;
    W1s[wr][wc+2] = w1v.z; W1s[wr][wc+3] = w1v.w;
    float4 w3v = *(const float4*)(W3 + (size_t)(k0 + wr) * N + bn + wc);
    W3s[wr][wc+0] = w3v.x; W3s[wr][wc+1] = w3v.y;
    W3s[wr][wc+2] = w3v.z; W3s[wr][wc+3] = w3v.w;
    __syncthreads();
#pragma unroll
    for (int kk = 0; kk < 16; ++kk) {
      float a0[4], w1r[4], w3r[4];
#pragma unroll
      for (int i = 0; i < 4; ++i) a0[i] = As[kk][ty*4 + i];
#pragma unroll
      for (int j = 0; j < 4; ++j) { w1r[j] = W1s[kk][tx*4 + j]; w3r[j] = W3s[kk][tx*4 + j]; }
#pragma unroll
      for (int i = 0; i < 4; ++i)
#pragma unroll
        for (int j = 0; j < 4; ++j) {
          acc1[i][j] += a0[i] * w1r[j];
          acc3[i][j] += a0[i] * w3r[j];
        }
    }
    __syncthreads();
  }
#pragma unroll
  for (int i = 0; i < 4; ++i) {
    int m = bm + ty*4 + i;
#pragma unroll
    for (int j = 0; j < 4; ++j) {
      int n = bn + tx*4 + j;
      float gg = acc1[i][j];
      float gelu = 0.5f * gg * (1.0f + erff(gg * 0.70710678118654752f));
      H[(size_t)m * N + n] = gelu * acc3[i][j];
    }
  }
}

// ---------------- MoE down: resid += coef * (H @ W2), skip if coef==0 ----------------
__global__ __launch_bounds__(256) void moe_down(const float* __restrict__ H,
                                                const float* __restrict__ W2,
                                                float* __restrict__ resid,
                                                const float* __restrict__ coef, int e) {
  int bm = blockIdx.y * 64, bn = blockIdx.x * 64;
  int b = bm / S_;
  float cf = coef[e * B_ + b];
  if (cf == 0.0f) return;
  const int K = DE_, N = D_;
  __shared__ float As[16][64];
  __shared__ float Ws[16][64];
  int tid = threadIdx.x;
  int tx = tid & 15, ty = tid >> 4;
  int ar = tid >> 2, ac4 = (tid & 3) * 4;
  int wr = tid >> 4, wc = (tid & 15) * 4;
  float acc[4][4] = {};
  for (int k0 = 0; k0 < K; k0 += 16) {
    float4 av = *(const float4*)(H + (size_t)(bm + ar) * K + k0 + ac4);
    As[ac4+0][ar] = av.x; As[ac4+1][ar] = av.y; As[ac4+2][ar] = av.z; As[ac4+3][ar] = av.w;
    float4 wv = *(const float4*)(W2 + (size_t)(k0 + wr) * N + bn + wc);
    Ws[wr][wc+0] = wv.x; Ws[wr][wc+1] = wv.y;
    Ws[wr][wc+2] = wv.z; Ws[wr][wc+3] = wv.w;
    __syncthreads();
#pragma unroll
    for (int kk = 0; kk < 16; ++kk) {
      float a0[4], w0[4];
#pragma unroll
      for (int i = 0; i < 4; ++i) a0[i] = As[kk][ty*4 + i];
#pragma unroll
      for (int j = 0; j < 4; ++j) w0[j] = Ws[kk][tx*4 + j];
#pragma unroll
      for (int i = 0; i < 4; ++i)
#pragma unroll
        for (int j = 0; j < 4; ++j) acc[i][j] += a0[i] * w0[j];
    }
    __syncthreads();
  }
#pragma unroll
  for (int i = 0; i < 4; ++i) {
    int m = bm + ty*4 + i;
#pragma unroll
    for (int j = 0; j < 4; ++j) {
      int n = bn + tx*4 + j;
      resid[(size_t)m * N + n] += cf * acc[i][j];
    }
  }
}

// ---------------- MoE routing coefficients ----------------
__global__ void coef_kernel(const int* __restrict__ langs, float* __restrict__ coef) {
  int t = threadIdx.x;
  if (t < NE_ * B_) {
    int e = t / B_, b = t % B_;
    int l0 = langs[b*2], l1 = langs[b*2 + 1];
    int counts = (l0 > 3) + (l1 > 3);
    float rw = (counts == 0) ? 1.0f : 1.0f / (float)counts;
    int code = 4 + e;
    bool m = (l0 == code) || (l1 == code);
    coef[e * B_ + b] = m ? rw : 0.0f;
  }
}

extern "C" void kernel_launch(void* const* d_in, const int* in_sizes, int n_in,
                              void* d_out, int out_size, void* d_ws, size_t ws_size,
                              hipStream_t stream) {
  const float* hidden = (const float*)d_in[0];
  const float* enc    = (const float*)d_in[1];
  const float* amask  = (const float*)d_in[2];
  const float* emask  = (const float*)d_in[3];
  const int*   langs  = (const int*)d_in[4];
  const float* ln1g = (const float*)d_in[5];
  const float* ln1b = (const float*)d_in[6];
  const float* saqw = (const float*)d_in[7];
  const float* saqb = (const float*)d_in[8];
  const float* sakw = (const float*)d_in[9];
  const float* sakb = (const float*)d_in[10];
  const float* savw = (const float*)d_in[11];
  const float* savb = (const float*)d_in[12];
  const float* saow = (const float*)d_in[13];
  const float* saob = (const float*)d_in[14];
  const float* ln2g = (const float*)d_in[15];
  const float* ln2b = (const float*)d_in[16];
  const float* caqw = (const float*)d_in[17];
  const float* caqb = (const float*)d_in[18];
  const float* cakw = (const float*)d_in[19];
  const float* cakb = (const float*)d_in[20];
  const float* cavw = (const float*)d_in[21];
  const float* cavb = (const float*)d_in[22];
  const float* caow = (const float*)d_in[23];
  const float* caob = (const float*)d_in[24];
  const float* ln3g = (const float*)d_in[25];
  const float* ln3b = (const float*)d_in[26];
  const float* w1   = (const float*)d_in[27];
  const float* w2   = (const float*)d_in[28];
  const float* w3   = (const float*)d_in[29];

  float* resid = (float*)d_out;                 // residual stream lives in d_out (fp32, B*S*D)

  float* ws = (float*)d_ws;
  float* xln   = ws;  ws += B_*S_*D_;           // 1,048,576
  float* qbuf  = ws;  ws += B_*S_*D_;           // 1,048,576
  float* kbuf  = ws;  ws += B_*SK_*NKV_*HD_;    //   524,288
  float* vbuf  = ws;  ws += B_*SK_*NKV_*HD_;    //   524,288
  float* abuf  = ws;  ws += B_*S_*D_;           // 1,048,576
  float* Hbuf  = ws;  ws += B_*S_*DE_;          // 4,194,304 (MoE hidden OR attention scores)
  float* coef  = ws;  ws += 64;                 // total ~33.6 MB (same as passing round)
  float* scb   = Hbuf;                          // scores alias: self 4*16*256*256, cross-half 2*16*256*512

  dim3 blk(256);
  const int M = B_ * S_;       // 1024
  const int MK = B_ * SK_;     // 2048
  const float qscale = 0.125f; // HD^-0.5

  // ---- self attention ----
  ln_kernel<<<M, blk, 0, stream>>>(hidden, ln1g, ln1b, xln);
  gemm_bias<<<dim3(D_/64, M/64), blk, 0, stream>>>(xln, saqw, saqb, nullptr, qbuf, qscale, M, D_, D_);
  gemm_bias<<<dim3((NKV_*HD_)/64, M/64), blk, 0, stream>>>(xln, sakw, sakb, nullptr, kbuf, 1.0f, M, NKV_*HD_, D_);
  gemm_bias<<<dim3((NKV_*HD_)/64, M/64), blk, 0, stream>>>(xln, savw, savb, nullptr, vbuf, 1.0f, M, NKV_*HD_, D_);
  qk_kernel<<<dim3(S_/64, S_/64, 4*NH_), blk, 0, stream>>>(qbuf, kbuf, amask, scb, 0, S_);
  softmax_kernel<<<(4*NH_*S_)/4, blk, 0, stream>>>(scb, S_, 4*NH_*S_);
  pv_kernel<<<dim3(S_/64, 4*NH_), blk, 0, stream>>>(scb, vbuf, abuf, 0, S_);
  // resid (d_out) = abuf@ow + ob + hidden   (fully overwrites d_out before any read of it)
  gemm_bias<<<dim3(D_/64, M/64), blk, 0, stream>>>(abuf, saow, saob, hidden, resid, 1.0f, M, D_, D_);

  // ---- cross attention ----
  ln_kernel<<<M, blk, 0, stream>>>(resid, ln2g, ln2b, xln);
  gemm_bias<<<dim3(D_/64, M/64), blk, 0, stream>>>(xln, caqw, caqb, nullptr, qbuf, qscale, M, D_, D_);
  gemm_bias<<<dim3((NKV_*HD_)/64, MK/64), blk, 0, stream>>>(enc, cakw, cakb, nullptr, kbuf, 1.0f, MK, NKV_*HD_, D_);
  gemm_bias<<<dim3((NKV_*HD_)/64, MK/64), blk, 0, stream>>>(enc, cavw, cavb, nullptr, vbuf, 1.0f, MK, NKV_*HD_, D_);
  for (int b0 = 0; b0 < B_; b0 += 2) {   // 2 batches/pass so scores fit the Hbuf alias
    qk_kernel<<<dim3(SK_/64, S_/64, 2*NH_), blk, 0, stream>>>(qbuf, kbuf, emask, scb, b0, SK_);
    softmax_kernel<<<(2*NH_*S_)/4, blk, 0, stream>>>(scb, SK_, 2*NH_*S_);
    pv_kernel<<<dim3(S_/64, 2*NH_), blk, 0, stream>>>(scb, vbuf, abuf, b0, SK_);
  }
  gemm_bias<<<dim3(D_/64, M/64), blk, 0, stream>>>(abuf, caow, caob, resid, resid, 1.0f, M, D_, D_);

  // ---- MoE ----
  ln_kernel<<<M, blk, 0, stream>>>(resid, ln3g, ln3b, xln);
  coef_kernel<<<1, 64, 0, stream>>>(langs, coef);
  for (int e = 0; e < NE_; ++e) {
    moe_gate<<<dim3(DE_/64, M/64), blk, 0, stream>>>(xln,
        w1 + (size_t)e * D_ * DE_, w3 + (size_t)e * D_ * DE_, Hbuf, coef, e);
    moe_down<<<dim3(D_/64, M/64), blk, 0, stream>>>(Hbuf,
        w2 + (size_t)e * DE_ * D_, resid, coef, e);
  }
}

// Round 4
// 861.918 us; speedup vs baseline: 4.4152x; 2.9011x over previous
//
#include <hip/hip_runtime.h>
#include <math.h>

#define B_   4
#define S_   256
#define SK_  512
#define D_   1024
#define NH_  16
#define NKV_ 4
#define HD_  64
#define DE_  4096
#define NE_  8

typedef __attribute__((ext_vector_type(8))) short bf16x8;
typedef __attribute__((ext_vector_type(4))) float f32x4;

__device__ __forceinline__ unsigned short f2b(float f) {
  union { float f; unsigned u; } v; v.f = f;
  unsigned r = v.u + 0x7FFF + ((v.u >> 16) & 1);   // RNE
  return (unsigned short)(r >> 16);
}

// ---- MFMA tile helpers: 64x64 block tile, K-step 32, 256 threads (4 waves 2x2) ----
// LDS layouts: As[m][k] k-contiguous, Ws[n][k] k-contiguous (W transposed at staging),
// row stride 40 bf16 elems (80B: keeps b128 16B-aligned, spreads banks).

__device__ __forceinline__ void stage_A_f32(const float* __restrict__ A, int lda, int k0, short* As) {
  int tid = threadIdx.x;
  int am = tid >> 2, ak8 = (tid & 3) * 8;
  const float* ap = A + (size_t)am * lda + k0 + ak8;
  float4 a0 = *(const float4*)ap;
  float4 a1 = *(const float4*)(ap + 4);
  const float* f0 = (const float*)&a0;
  const float* f1 = (const float*)&a1;
  bf16x8 v;
  v[0]=f2b(f0[0]); v[1]=f2b(f0[1]); v[2]=f2b(f0[2]); v[3]=f2b(f0[3]);
  v[4]=f2b(f1[0]); v[5]=f2b(f1[1]); v[6]=f2b(f1[2]); v[7]=f2b(f1[3]);
  *(bf16x8*)(As + am * 40 + ak8) = v;
}

__device__ __forceinline__ void stage_A_bf16(const short* __restrict__ A, int lda, int k0, short* As) {
  int tid = threadIdx.x;
  int am = tid >> 2, ak8 = (tid & 3) * 8;
  *(bf16x8*)(As + am * 40 + ak8) = *(const bf16x8*)(A + (size_t)am * lda + k0 + ak8);
}

__device__ __forceinline__ void stage_W_f32(const float* __restrict__ W, int ldw, int k0, short* Ws) {
  int tid = threadIdx.x;
  int wk2 = (tid & 15) * 2, wn4 = (tid >> 4) * 4;
  const float* wp = W + (size_t)(k0 + wk2) * ldw + wn4;
  float4 w0 = *(const float4*)wp;
  float4 w1 = *(const float4*)(wp + ldw);
  const float* f0 = (const float*)&w0;
  const float* f1 = (const float*)&w1;
#pragma unroll
  for (int c = 0; c < 4; ++c) {
    unsigned p = (unsigned)f2b(f0[c]) | ((unsigned)f2b(f1[c]) << 16);
    *(unsigned*)(Ws + (wn4 + c) * 40 + wk2) = p;
  }
}

__device__ __forceinline__ void mfma_quad(const short* As, const short* Ws, f32x4 acc[2][2]) {
  int lane = threadIdx.x & 63, wv = threadIdx.x >> 6;
  int wm = (wv & 1) * 32, wn = (wv >> 1) * 32;
  int quad = lane >> 4, l16 = lane & 15;
  bf16x8 a0 = *(const bf16x8*)(As + (wm + l16) * 40 + quad * 8);
  bf16x8 a1 = *(const bf16x8*)(As + (wm + 16 + l16) * 40 + quad * 8);
  bf16x8 b0 = *(const bf16x8*)(Ws + (wn + l16) * 40 + quad * 8);
  bf16x8 b1 = *(const bf16x8*)(Ws + (wn + 16 + l16) * 40 + quad * 8);
  acc[0][0] = __builtin_amdgcn_mfma_f32_16x16x32_bf16(a0, b0, acc[0][0], 0, 0, 0);
  acc[0][1] = __builtin_amdgcn_mfma_f32_16x16x32_bf16(a0, b1, acc[0][1], 0, 0, 0);
  acc[1][0] = __builtin_amdgcn_mfma_f32_16x16x32_bf16(a1, b0, acc[1][0], 0, 0, 0);
  acc[1][1] = __builtin_amdgcn_mfma_f32_16x16x32_bf16(a1, b1, acc[1][1], 0, 0, 0);
}

// body: C[bm..bm+63, bn..bn+63] = scale*(A@W + bias) [+resid]
__device__ __forceinline__ void gemm_body(const float* A, const float* W, const float* bias,
                                          const float* resid, float* C, float scale,
                                          int N, int K, int bm, int bn,
                                          short* As, short* Ws) {
  f32x4 z4 = {0.f, 0.f, 0.f, 0.f};
  f32x4 acc[2][2] = {{z4, z4}, {z4, z4}};
  const float* Ab = A + (size_t)bm * K;
  const float* Wb = W + bn;
  for (int k0 = 0; k0 < K; k0 += 32) {
    stage_A_f32(Ab, K, k0, As);
    stage_W_f32(Wb, N, k0, Ws);
    __syncthreads();
    mfma_quad(As, Ws, acc);
    __syncthreads();
  }
  int lane = threadIdx.x & 63, wv = threadIdx.x >> 6;
  int wm = (wv & 1) * 32, wn = (wv >> 1) * 32;
  int quad = lane >> 4, l16 = lane & 15;
#pragma unroll
  for (int i = 0; i < 2; ++i)
#pragma unroll
    for (int j = 0; j < 2; ++j)
#pragma unroll
      for (int r = 0; r < 4; ++r) {
        int m = bm + wm + i * 16 + quad * 4 + r;
        int n = bn + wn + j * 16 + l16;
        float v = (acc[i][j][r] + bias[n]) * scale;
        if (resid) v += resid[(size_t)m * N + n];
        C[(size_t)m * N + n] = v;
      }
}

// ---------------- fused QKV projection (z=0:Q, 1:K, 2:V) ----------------
__global__ __launch_bounds__(256) void qkv_mfma(const float* __restrict__ xq, const float* __restrict__ xkv,
                                                const float* qw, const float* qb,
                                                const float* kw, const float* kb,
                                                const float* vw, const float* vb,
                                                float* qo, float* ko, float* vo,
                                                int Mq, int Mkv) {
  int z = blockIdx.z;
  const float *A, *W, *bias; float* out; int M, N; float scale;
  if (z == 0)      { A = xq;  W = qw; bias = qb; out = qo; M = Mq;  N = D_;  scale = 0.125f; }
  else if (z == 1) { A = xkv; W = kw; bias = kb; out = ko; M = Mkv; N = 256; scale = 1.0f; }
  else             { A = xkv; W = vw; bias = vb; out = vo; M = Mkv; N = 256; scale = 1.0f; }
  int bn = blockIdx.x * 64, bm = blockIdx.y * 64;
  if (bm >= M || bn >= N) return;
  __shared__ short As[64 * 40], Ws[64 * 40];
  gemm_body(A, W, bias, nullptr, out, scale, N, D_, bm, bn, As, Ws);
}

// ---------------- generic MFMA GEMM (O-proj with residual) ----------------
__global__ __launch_bounds__(256) void gemm_mfma(const float* __restrict__ A, const float* __restrict__ W,
                                                 const float* __restrict__ bias,
                                                 const float* resid, float* C,
                                                 float scale, int N, int K) {
  int bn = blockIdx.x * 64, bm = blockIdx.y * 64;
  __shared__ short As[64 * 40], Ws[64 * 40];
  gemm_body(A, W, bias, resid, C, scale, N, K, bm, bn, As, Ws);
}

// ---------------- MoE gate, all experts in one dispatch ----------------
// H[slot][b] = gelu(xln@W1e) * (xln@W3e), bf16
__global__ __launch_bounds__(256) void moe_gate_mfma(const float* __restrict__ xln,
                                                     const float* __restrict__ W1,
                                                     const float* __restrict__ W3,
                                                     short* __restrict__ Hs,
                                                     const float* __restrict__ coef,
                                                     const int* __restrict__ slot) {
  int e = blockIdx.z;
  int bn = blockIdx.x * 64, bm = blockIdx.y * 64;
  int b = bm >> 8;
  if (coef[e * B_ + b] == 0.0f) return;
  int sl = slot[e * B_ + b];
  __shared__ short As[64 * 40], W1s[64 * 40], W3s[64 * 40];
  f32x4 z4 = {0.f, 0.f, 0.f, 0.f};
  f32x4 acc1[2][2] = {{z4, z4}, {z4, z4}};
  f32x4 acc3[2][2] = {{z4, z4}, {z4, z4}};
  const float* Ab  = xln + (size_t)bm * D_;
  const float* W1b = W1 + (size_t)e * D_ * DE_ + bn;
  const float* W3b = W3 + (size_t)e * D_ * DE_ + bn;
  for (int k0 = 0; k0 < D_; k0 += 32) {
    stage_A_f32(Ab, D_, k0, As);
    stage_W_f32(W1b, DE_, k0, W1s);
    stage_W_f32(W3b, DE_, k0, W3s);
    __syncthreads();
    mfma_quad(As, W1s, acc1);
    mfma_quad(As, W3s, acc3);
    __syncthreads();
  }
  int lane = threadIdx.x & 63, wv = threadIdx.x >> 6;
  int wm = (wv & 1) * 32, wn = (wv >> 1) * 32;
  int quad = lane >> 4, l16 = lane & 15;
  int rb = bm & 255;
  short* Hp = Hs + ((size_t)(sl * B_ + b) * S_ + rb) * DE_;
#pragma unroll
  for (int i = 0; i < 2; ++i)
#pragma unroll
    for (int j = 0; j < 2; ++j)
#pragma unroll
      for (int r = 0; r < 4; ++r) {
        int lm = wm + i * 16 + quad * 4 + r;
        int n  = bn + wn + j * 16 + l16;
        float c1 = acc1[i][j][r], c3 = acc3[i][j][r];
        float g = 0.5f * c1 * (1.0f + erff(c1 * 0.70710678118654752f));
        Hp[(size_t)lm * DE_ + n] = (short)f2b(g * c3);
      }
}

// ---------------- MoE down, all experts + 4-way K-split, atomic epilogue ----------------
__global__ __launch_bounds__(256) void moe_down_mfma(const short* __restrict__ Hs,
                                                     const float* __restrict__ W2,
                                                     float* resid,
                                                     const float* __restrict__ coef,
                                                     const int* __restrict__ slot) {
  int z = blockIdx.z;
  int e = z >> 2, kc = z & 3;
  int bn = blockIdx.x * 64, bm = blockIdx.y * 64;
  int b = bm >> 8;
  float cf = coef[e * B_ + b];
  if (cf == 0.0f) return;
  int sl = slot[e * B_ + b];
  int rb = bm & 255;
  __shared__ short As[64 * 40], Ws[64 * 40];
  f32x4 z4 = {0.f, 0.f, 0.f, 0.f};
  f32x4 acc[2][2] = {{z4, z4}, {z4, z4}};
  const short* Ab = Hs + ((size_t)(sl * B_ + b) * S_ + rb) * DE_ + kc * 1024;
  const float* Wb = W2 + (size_t)e * DE_ * D_ + (size_t)kc * 1024 * D_ + bn;
  for (int k0 = 0; k0 < 1024; k0 += 32) {
    stage_A_bf16(Ab, DE_, k0, As);
    stage_W_f32(Wb, D_, k0, Ws);
    __syncthreads();
    mfma_quad(As, Ws, acc);
    __syncthreads();
  }
  int lane = threadIdx.x & 63, wv = threadIdx.x >> 6;
  int wm = (wv & 1) * 32, wn = (wv >> 1) * 32;
  int quad = lane >> 4, l16 = lane & 15;
#pragma unroll
  for (int i = 0; i < 2; ++i)
#pragma unroll
    for (int j = 0; j < 2; ++j)
#pragma unroll
      for (int r = 0; r < 4; ++r) {
        int m = bm + wm + i * 16 + quad * 4 + r;
        int n = bn + wn + j * 16 + l16;
        atomicAdd(&resid[(size_t)m * D_ + n], cf * acc[i][j][r]);
      }
}

// ---------------- layernorm ----------------
__global__ __launch_bounds__(256) void ln_kernel(const float* __restrict__ x,
                                                 const float* __restrict__ g,
                                                 const float* __restrict__ be,
                                                 float* __restrict__ y) {
  int row = blockIdx.x, tid = threadIdx.x;
  const float4 v = ((const float4*)(x + (size_t)row * D_))[tid];
  float s  = v.x + v.y + v.z + v.w;
  float s2 = v.x*v.x + v.y*v.y + v.z*v.z + v.w*v.w;
  __shared__ float r1[256], r2[256];
  r1[tid] = s; r2[tid] = s2; __syncthreads();
  for (int off = 128; off > 0; off >>= 1) {
    if (tid < off) { r1[tid] += r1[tid+off]; r2[tid] += r2[tid+off]; }
    __syncthreads();
  }
  float mean = r1[0] * (1.0f / D_);
  float var  = r2[0] * (1.0f / D_) - mean * mean;
  float inv  = rsqrtf(var + 1e-5f);
  float* yr = y + (size_t)row * D_;
  int c = tid * 4;
  yr[c]   = (v.x - mean) * inv * g[c]   + be[c];
  yr[c+1] = (v.y - mean) * inv * g[c+1] + be[c+1];
  yr[c+2] = (v.z - mean) * inv * g[c+2] + be[c+2];
  yr[c+3] = (v.w - mean) * inv * g[c+3] + be[c+3];
}

// ---------------- QK^T + mask (fp32 tile) ----------------
__global__ __launch_bounds__(256) void qk_kernel(const float* __restrict__ qb,
                                                 const float* __restrict__ kb,
                                                 const float* __restrict__ mask,
                                                 float* __restrict__ sc,
                                                 int b0, int SKV) {
  int z = blockIdx.z;
  int zb = z >> 4, h = z & 15;
  int b = b0 + zb;
  int kvh = h >> 2;
  int bq = blockIdx.y * 64, bk = blockIdx.x * 64;
  __shared__ float As[16][64];
  __shared__ float Bs[16][64];
  int tid = threadIdx.x;
  int tx = tid & 15, ty = tid >> 4;
  int ar = tid >> 2, ac4 = (tid & 3) * 4;
  float acc[4][4] = {};
  for (int k0 = 0; k0 < HD_; k0 += 16) {
    float4 av = *(const float4*)(qb + (size_t)(b*S_ + bq + ar) * D_ + h*HD_ + k0 + ac4);
    As[ac4+0][ar] = av.x; As[ac4+1][ar] = av.y; As[ac4+2][ar] = av.z; As[ac4+3][ar] = av.w;
    float4 bv = *(const float4*)(kb + (size_t)(b*SKV + bk + ar) * (NKV_*HD_) + kvh*HD_ + k0 + ac4);
    Bs[ac4+0][ar] = bv.x; Bs[ac4+1][ar] = bv.y; Bs[ac4+2][ar] = bv.z; Bs[ac4+3][ar] = bv.w;
    __syncthreads();
#pragma unroll
    for (int kk = 0; kk < 16; ++kk) {
      float a0[4], w0[4];
#pragma unroll
      for (int i = 0; i < 4; ++i) a0[i] = As[kk][ty*4 + i];
#pragma unroll
      for (int j = 0; j < 4; ++j) w0[j] = Bs[kk][tx*4 + j];
#pragma unroll
      for (int i = 0; i < 4; ++i)
#pragma unroll
        for (int j = 0; j < 4; ++j) acc[i][j] += a0[i] * w0[j];
    }
    __syncthreads();
  }
#pragma unroll
  for (int i = 0; i < 4; ++i) {
    int qi = bq + ty*4 + i;
#pragma unroll
    for (int j = 0; j < 4; ++j) {
      int kc = bk + tx*4 + j;
      sc[((size_t)(zb*NH_ + h) * S_ + qi) * SKV + kc] =
          acc[i][j] + mask[((size_t)(b*S_ + qi)) * SKV + kc];
    }
  }
}

// ---------------- row softmax, one wave per row ----------------
__global__ __launch_bounds__(256) void softmax_kernel(float* __restrict__ sc, int SKV, int nrows) {
  int row = blockIdx.x * 4 + (threadIdx.x >> 6);
  int lane = threadIdx.x & 63;
  if (row >= nrows) return;
  float* rp = sc + (size_t)row * SKV;
  float4 v[2];
  int nc = SKV >> 8;
  float mx = -1e30f;
#pragma unroll
  for (int c = 0; c < 2; ++c) {
    if (c < nc) {
      v[c] = *(float4*)(rp + c*256 + lane*4);
      mx = fmaxf(mx, fmaxf(fmaxf(v[c].x, v[c].y), fmaxf(v[c].z, v[c].w)));
    }
  }
#pragma unroll
  for (int m = 32; m > 0; m >>= 1) mx = fmaxf(mx, __shfl_xor(mx, m, 64));
  float ls = 0.f;
#pragma unroll
  for (int c = 0; c < 2; ++c) {
    if (c < nc) {
      v[c].x = __expf(v[c].x - mx); v[c].y = __expf(v[c].y - mx);
      v[c].z = __expf(v[c].z - mx); v[c].w = __expf(v[c].w - mx);
      ls += v[c].x + v[c].y + v[c].z + v[c].w;
    }
  }
#pragma unroll
  for (int m = 32; m > 0; m >>= 1) ls += __shfl_xor(ls, m, 64);
  float inv = 1.0f / ls;
#pragma unroll
  for (int c = 0; c < 2; ++c) {
    if (c < nc) {
      v[c].x *= inv; v[c].y *= inv; v[c].z *= inv; v[c].w *= inv;
      *(float4*)(rp + c*256 + lane*4) = v[c];
    }
  }
}

// ---------------- P @ V (fp32 tile) ----------------
__global__ __launch_bounds__(256) void pv_kernel(const float* __restrict__ sc,
                                                 const float* __restrict__ vb,
                                                 float* __restrict__ ob,
                                                 int b0, int SKV) {
  int z = blockIdx.y;
  int zb = z >> 4, h = z & 15;
  int b = b0 + zb;
  int kvh = h >> 2;
  int bq = blockIdx.x * 64;
  __shared__ float As[16][64];
  __shared__ float Bs[16][64];
  int tid = threadIdx.x;
  int tx = tid & 15, ty = tid >> 4;
  int ar = tid >> 2, ac4 = (tid & 3) * 4;
  int wr = tid >> 4, wc = (tid & 15) * 4;
  float acc[4][4] = {};
  for (int k0 = 0; k0 < SKV; k0 += 16) {
    float4 av = *(const float4*)(sc + ((size_t)(zb*NH_ + h) * S_ + bq + ar) * SKV + k0 + ac4);
    As[ac4+0][ar] = av.x; As[ac4+1][ar] = av.y; As[ac4+2][ar] = av.z; As[ac4+3][ar] = av.w;
    float4 bv = *(const float4*)(vb + (size_t)(b*SKV + k0 + wr) * (NKV_*HD_) + kvh*HD_ + wc);
    Bs[wr][wc+0] = bv.x; Bs[wr][wc+1] = bv.y;
    Bs[wr][wc+2] = bv.z; Bs[wr][wc+3] = bv.w;
    __syncthreads();
#pragma unroll
    for (int kk = 0; kk < 16; ++kk) {
      float a0[4], w0[4];
#pragma unroll
      for (int i = 0; i < 4; ++i) a0[i] = As[kk][ty*4 + i];
#pragma unroll
      for (int j = 0; j < 4; ++j) w0[j] = Bs[kk][tx*4 + j];
#pragma unroll
      for (int i = 0; i < 4; ++i)
#pragma unroll
        for (int j = 0; j < 4; ++j) acc[i][j] += a0[i] * w0[j];
    }
    __syncthreads();
  }
#pragma unroll
  for (int i = 0; i < 4; ++i) {
    int qi = bq + ty*4 + i;
#pragma unroll
    for (int j = 0; j < 4; ++j) {
      int d = tx*4 + j;
      ob[(size_t)(b*S_ + qi) * D_ + h*HD_ + d] = acc[i][j];
    }
  }
}

// ---------------- MoE routing coefficients + slots ----------------
__global__ void coef_kernel(const int* __restrict__ langs, float* __restrict__ coef,
                            int* __restrict__ slot) {
  int t = threadIdx.x;
  if (t < NE_ * B_) {
    int e = t >> 2, b = t & 3;
    int l0 = langs[b*2], l1 = langs[b*2 + 1];
    int counts = (l0 > 3) + (l1 > 3);
    float rw = (counts == 0) ? 1.0f : 1.0f / (float)counts;
    bool m = (l0 == 4 + e) || (l1 == 4 + e);
    coef[t] = m ? rw : 0.0f;
    int s = 0;
    for (int ep = 0; ep < e; ++ep) s += ((l0 == 4 + ep) || (l1 == 4 + ep)) ? 1 : 0;
    slot[t] = s;
  }
}

extern "C" void kernel_launch(void* const* d_in, const int* in_sizes, int n_in,
                              void* d_out, int out_size, void* d_ws, size_t ws_size,
                              hipStream_t stream) {
  const float* hidden = (const float*)d_in[0];
  const float* enc    = (const float*)d_in[1];
  const float* amask  = (const float*)d_in[2];
  const float* emask  = (const float*)d_in[3];
  const int*   langs  = (const int*)d_in[4];
  const float* ln1g = (const float*)d_in[5];
  const float* ln1b = (const float*)d_in[6];
  const float* saqw = (const float*)d_in[7];
  const float* saqb = (const float*)d_in[8];
  const float* sakw = (const float*)d_in[9];
  const float* sakb = (const float*)d_in[10];
  const float* savw = (const float*)d_in[11];
  const float* savb = (const float*)d_in[12];
  const float* saow = (const float*)d_in[13];
  const float* saob = (const float*)d_in[14];
  const float* ln2g = (const float*)d_in[15];
  const float* ln2b = (const float*)d_in[16];
  const float* caqw = (const float*)d_in[17];
  const float* caqb = (const float*)d_in[18];
  const float* cakw = (const float*)d_in[19];
  const float* cakb = (const float*)d_in[20];
  const float* cavw = (const float*)d_in[21];
  const float* cavb = (const float*)d_in[22];
  const float* caow = (const float*)d_in[23];
  const float* caob = (const float*)d_in[24];
  const float* ln3g = (const float*)d_in[25];
  const float* ln3b = (const float*)d_in[26];
  const float* w1   = (const float*)d_in[27];
  const float* w2   = (const float*)d_in[28];
  const float* w3   = (const float*)d_in[29];

  float* resid = (float*)d_out;                 // residual stream lives in d_out (fp32, B*S*D)

  float* ws = (float*)d_ws;
  float* xln   = ws;  ws += B_*S_*D_;           // 1,048,576
  float* qbuf  = ws;  ws += B_*S_*D_;           // 1,048,576
  float* kbuf  = ws;  ws += B_*SK_*NKV_*HD_;    //   524,288
  float* vbuf  = ws;  ws += B_*SK_*NKV_*HD_;    //   524,288
  float* abuf  = ws;  ws += B_*S_*D_;           // 1,048,576
  float* Hreg  = ws;  ws += B_*S_*DE_;          // 4,194,304 fp32 region (scores OR bf16 H[2 slots])
  float* coef  = ws;  ws += 32;
  int*   slot  = (int*)ws; ws += 32;            // total ~33.6 MB (same as passing round)
  float* scb   = Hreg;                          // fp32 scores alias
  short* Hs    = (short*)Hreg;                  // bf16 MoE hidden [2][B][S][DE] alias

  dim3 blk(256);
  const int M = B_ * S_;       // 1024

  // ---- self attention ----
  ln_kernel<<<M, blk, 0, stream>>>(hidden, ln1g, ln1b, xln);
  qkv_mfma<<<dim3(16, 16, 3), blk, 0, stream>>>(xln, xln, saqw, saqb, sakw, sakb, savw, savb,
                                                qbuf, kbuf, vbuf, M, M);
  qk_kernel<<<dim3(S_/64, S_/64, 4*NH_), blk, 0, stream>>>(qbuf, kbuf, amask, scb, 0, S_);
  softmax_kernel<<<(4*NH_*S_)/4, blk, 0, stream>>>(scb, S_, 4*NH_*S_);
  pv_kernel<<<dim3(S_/64, 4*NH_), blk, 0, stream>>>(scb, vbuf, abuf, 0, S_);
  gemm_mfma<<<dim3(16, 16), blk, 0, stream>>>(abuf, saow, saob, hidden, resid, 1.0f, D_, D_);

  // ---- cross attention ----
  ln_kernel<<<M, blk, 0, stream>>>(resid, ln2g, ln2b, xln);
  qkv_mfma<<<dim3(16, 32, 3), blk, 0, stream>>>(xln, enc, caqw, caqb, cakw, cakb, cavw, cavb,
                                                qbuf, kbuf, vbuf, M, B_*SK_);
  for (int b0 = 0; b0 < B_; b0 += 2) {   // 2 batches/pass so fp32 scores fit the H region
    qk_kernel<<<dim3(SK_/64, S_/64, 2*NH_), blk, 0, stream>>>(qbuf, kbuf, emask, scb, b0, SK_);
    softmax_kernel<<<(2*NH_*S_)/4, blk, 0, stream>>>(scb, SK_, 2*NH_*S_);
    pv_kernel<<<dim3(S_/64, 2*NH_), blk, 0, stream>>>(scb, vbuf, abuf, b0, SK_);
  }
  gemm_mfma<<<dim3(16, 16), blk, 0, stream>>>(abuf, caow, caob, resid, resid, 1.0f, D_, D_);

  // ---- MoE ----
  ln_kernel<<<M, blk, 0, stream>>>(resid, ln3g, ln3b, xln);
  coef_kernel<<<1, 64, 0, stream>>>(langs, coef, slot);
  moe_gate_mfma<<<dim3(DE_/64, M/64, NE_), blk, 0, stream>>>(xln, w1, w3, Hs, coef, slot);
  moe_down_mfma<<<dim3(D_/64, M/64, NE_*4), blk, 0, stream>>>(Hs, w2, resid, coef, slot);
}

// Round 5
// 820.017 us; speedup vs baseline: 4.6408x; 1.0511x over previous
//
#include <hip/hip_runtime.h>
#include <math.h>

#define B_   4
#define S_   256
#define SK_  512
#define D_   1024
#define NH_  16
#define NKV_ 4
#define HD_  64
#define DE_  4096
#define NE_  8

typedef __attribute__((ext_vector_type(8))) short bf16x8;
typedef __attribute__((ext_vector_type(4))) float f32x4;

struct __align__(8) s4 { short x, y, z, w; };

#define MFMA(a,b,c) __builtin_amdgcn_mfma_f32_16x16x32_bf16(a,b,c,0,0,0)

__device__ __forceinline__ unsigned short f2b(float f) {  // RNE
  union { float f; unsigned u; } v; v.f = f;
  unsigned r = v.u + 0x7FFF + ((v.u >> 16) & 1);
  return (unsigned short)(r >> 16);
}

// B-fragment: 8 bf16 for k..k+7 at fixed n, from fp32 W[k][n] (ldw = N).
// 16 lanes share k, consecutive n -> 64B coalesced segments per k-row.
__device__ __forceinline__ bf16x8 load_w_frag(const float* __restrict__ wp, int ldw) {
  union { unsigned u[4]; bf16x8 v; } r;
#pragma unroll
  for (int j = 0; j < 4; ++j) {
    unsigned u0 = __float_as_uint(wp[(size_t)(2*j)   * ldw]) + 0x8000u;  // round-half-up
    unsigned u1 = __float_as_uint(wp[(size_t)(2*j+1) * ldw]) + 0x8000u;
    r.u[j] = (u0 >> 16) | (u1 & 0xffff0000u);
  }
  return r.v;
}

// ---------------- layernorm: fp32 in, bf16 out ----------------
__global__ __launch_bounds__(256) void ln_kernel(const float* __restrict__ x,
                                                 const float* __restrict__ g,
                                                 const float* __restrict__ be,
                                                 short* __restrict__ y) {
  int row = blockIdx.x, tid = threadIdx.x;
  const float4 v = ((const float4*)(x + (size_t)row * D_))[tid];
  float s  = v.x + v.y + v.z + v.w;
  float s2 = v.x*v.x + v.y*v.y + v.z*v.z + v.w*v.w;
  __shared__ float r1[256], r2[256];
  r1[tid] = s; r2[tid] = s2; __syncthreads();
  for (int off = 128; off > 0; off >>= 1) {
    if (tid < off) { r1[tid] += r1[tid+off]; r2[tid] += r2[tid+off]; }
    __syncthreads();
  }
  float mean = r1[0] * (1.0f / D_);
  float var  = r2[0] * (1.0f / D_) - mean * mean;
  float inv  = rsqrtf(var + 1e-5f);
  int c = tid * 4;
  s4 o;
  o.x = (short)f2b((v.x - mean) * inv * g[c]   + be[c]);
  o.y = (short)f2b((v.y - mean) * inv * g[c+1] + be[c+1]);
  o.z = (short)f2b((v.z - mean) * inv * g[c+2] + be[c+2]);
  o.w = (short)f2b((v.w - mean) * inv * g[c+3] + be[c+3]);
  *(s4*)(y + (size_t)row * D_ + c) = o;
}

// ---------------- cast fp32 -> bf16 ----------------
__global__ void cast_f2b(const float* __restrict__ in, short* __restrict__ out, int n) {
  int i = (blockIdx.x * 256 + threadIdx.x) * 4;
  if (i < n) {
    float4 v = *(const float4*)(in + i);
    s4 o; o.x=(short)f2b(v.x); o.y=(short)f2b(v.y); o.z=(short)f2b(v.z); o.w=(short)f2b(v.w);
    *(s4*)(out + i) = o;
  }
}

// ---------------- projection: Cb = bf16((A@W + bias) * scale) ----------------
__global__ __launch_bounds__(256) void proj_mfma(const short* __restrict__ A,
                                                 const float* __restrict__ W,
                                                 const float* __restrict__ bias,
                                                 short* __restrict__ Cb,
                                                 float scale, int N, int K) {
  int bn = blockIdx.x * 64, bm = blockIdx.y * 64;
  int lane = threadIdx.x & 63, wv = threadIdx.x >> 6;
  int wm = (wv & 1) * 32, wn = (wv >> 1) * 32;
  int quad = lane >> 4, l16 = lane & 15;
  f32x4 z4 = {0.f,0.f,0.f,0.f};
  f32x4 acc[2][2] = {{z4,z4},{z4,z4}};
  const short* a0p = A + (size_t)(bm + wm + l16) * K;
  const short* a1p = a0p + (size_t)16 * K;
  const float* w0p = W + bn + wn + l16;
  const float* w1p = w0p + 16;
#pragma unroll 2
  for (int k0 = 0; k0 < K; k0 += 32) {
    int ka = k0 + quad * 8;
    bf16x8 a0 = *(const bf16x8*)(a0p + ka);
    bf16x8 a1 = *(const bf16x8*)(a1p + ka);
    bf16x8 b0 = load_w_frag(w0p + (size_t)ka * N, N);
    bf16x8 b1 = load_w_frag(w1p + (size_t)ka * N, N);
    acc[0][0] = MFMA(a0, b0, acc[0][0]);
    acc[0][1] = MFMA(a0, b1, acc[0][1]);
    acc[1][0] = MFMA(a1, b0, acc[1][0]);
    acc[1][1] = MFMA(a1, b1, acc[1][1]);
  }
#pragma unroll
  for (int i = 0; i < 2; ++i)
#pragma unroll
    for (int j = 0; j < 2; ++j) {
      int n = bn + wn + j*16 + l16;
      float bs = bias[n];
#pragma unroll
      for (int r = 0; r < 4; ++r) {
        int m = bm + wm + i*16 + quad*4 + r;
        Cb[(size_t)m * N + n] = (short)f2b((acc[i][j][r] + bs) * scale);
      }
    }
}

// ---------------- V projection with transposed output: vT[b][256 d][512 skv] ----------------
__global__ __launch_bounds__(256) void proj_v_mfma(const short* __restrict__ A,
                                                   const float* __restrict__ W,
                                                   const float* __restrict__ bias,
                                                   short* __restrict__ vT,
                                                   int SKV, int K) {
  const int N = 256;
  int bn = blockIdx.x * 64, bm = blockIdx.y * 64;
  int lane = threadIdx.x & 63, wv = threadIdx.x >> 6;
  int wm = (wv & 1) * 32, wn = (wv >> 1) * 32;
  int quad = lane >> 4, l16 = lane & 15;
  f32x4 z4 = {0.f,0.f,0.f,0.f};
  f32x4 acc[2][2] = {{z4,z4},{z4,z4}};
  const short* a0p = A + (size_t)(bm + wm + l16) * K;
  const short* a1p = a0p + (size_t)16 * K;
  const float* w0p = W + bn + wn + l16;
  const float* w1p = w0p + 16;
#pragma unroll 2
  for (int k0 = 0; k0 < K; k0 += 32) {
    int ka = k0 + quad * 8;
    bf16x8 a0 = *(const bf16x8*)(a0p + ka);
    bf16x8 a1 = *(const bf16x8*)(a1p + ka);
    bf16x8 b0 = load_w_frag(w0p + (size_t)ka * N, N);
    bf16x8 b1 = load_w_frag(w1p + (size_t)ka * N, N);
    acc[0][0] = MFMA(a0, b0, acc[0][0]);
    acc[0][1] = MFMA(a0, b1, acc[0][1]);
    acc[1][0] = MFMA(a1, b0, acc[1][0]);
    acc[1][1] = MFMA(a1, b1, acc[1][1]);
  }
  __shared__ float T[64][65];
#pragma unroll
  for (int i = 0; i < 2; ++i)
#pragma unroll
    for (int j = 0; j < 2; ++j) {
      int nl = wn + j*16 + l16;
      float bs = bias[bn + nl];
#pragma unroll
      for (int r = 0; r < 4; ++r)
        T[nl][wm + i*16 + quad*4 + r] = acc[i][j][r] + bs;
    }
  __syncthreads();
  int t = threadIdx.x;
  int nl = t >> 2, m4 = (t & 3) * 16;
  int bb = bm / SKV, skv0 = bm % SKV;
  short* dst = vT + ((size_t)bb * 256 + bn + nl) * 512 + skv0 + m4;
  bf16x8 o0, o1;
#pragma unroll
  for (int ii = 0; ii < 8; ++ii) o0[ii] = (short)f2b(T[nl][m4 + ii]);
#pragma unroll
  for (int ii = 0; ii < 8; ++ii) o1[ii] = (short)f2b(T[nl][m4 + 8 + ii]);
  *(bf16x8*)dst = o0;
  *(bf16x8*)(dst + 8) = o1;
}

// ---------------- O projection: out fp32 = A@W + bias + residin ----------------
__global__ __launch_bounds__(256) void proj_o_mfma(const short* __restrict__ A,
                                                   const float* __restrict__ W,
                                                   const float* __restrict__ bias,
                                                   const float* __restrict__ rin,
                                                   float* __restrict__ C, int N, int K) {
  int bn = blockIdx.x * 64, bm = blockIdx.y * 64;
  int lane = threadIdx.x & 63, wv = threadIdx.x >> 6;
  int wm = (wv & 1) * 32, wn = (wv >> 1) * 32;
  int quad = lane >> 4, l16 = lane & 15;
  f32x4 z4 = {0.f,0.f,0.f,0.f};
  f32x4 acc[2][2] = {{z4,z4},{z4,z4}};
  const short* a0p = A + (size_t)(bm + wm + l16) * K;
  const short* a1p = a0p + (size_t)16 * K;
  const float* w0p = W + bn + wn + l16;
  const float* w1p = w0p + 16;
#pragma unroll 2
  for (int k0 = 0; k0 < K; k0 += 32) {
    int ka = k0 + quad * 8;
    bf16x8 a0 = *(const bf16x8*)(a0p + ka);
    bf16x8 a1 = *(const bf16x8*)(a1p + ka);
    bf16x8 b0 = load_w_frag(w0p + (size_t)ka * N, N);
    bf16x8 b1 = load_w_frag(w1p + (size_t)ka * N, N);
    acc[0][0] = MFMA(a0, b0, acc[0][0]);
    acc[0][1] = MFMA(a0, b1, acc[0][1]);
    acc[1][0] = MFMA(a1, b0, acc[1][0]);
    acc[1][1] = MFMA(a1, b1, acc[1][1]);
  }
#pragma unroll
  for (int i = 0; i < 2; ++i)
#pragma unroll
    for (int j = 0; j < 2; ++j) {
      int n = bn + wn + j*16 + l16;
      float bs = bias[n];
#pragma unroll
      for (int r = 0; r < 4; ++r) {
        int m = bm + wm + i*16 + quad*4 + r;
        C[(size_t)m * N + n] = acc[i][j][r] + bs + rin[(size_t)m * N + n];
      }
    }
}

// ---------------- QK^T + mask -> fp32 scores ----------------
__global__ __launch_bounds__(256) void qk_mfma(const short* __restrict__ Q,
                                               const short* __restrict__ Kb,
                                               const float* __restrict__ mask,
                                               float* __restrict__ sc,
                                               int b0, int SKV) {
  int z = blockIdx.z, zb = z >> 4, h = z & 15, b = b0 + zb, kvh = h >> 2;
  int bk = blockIdx.x * 64, bq = blockIdx.y * 64;
  int lane = threadIdx.x & 63, wv = threadIdx.x >> 6;
  int wm = (wv & 1) * 32, wn = (wv >> 1) * 32;
  int quad = lane >> 4, l16 = lane & 15;
  f32x4 z4 = {0.f,0.f,0.f,0.f};
  f32x4 acc[2][2] = {{z4,z4},{z4,z4}};
  const short* q0 = Q + (size_t)(b*S_ + bq + wm + l16) * D_ + h * HD_;
  const short* q1 = q0 + (size_t)16 * D_;
  const short* k0p = Kb + (size_t)(b*SKV + bk + wn + l16) * (NKV_*HD_) + kvh * HD_;
  const short* k1p = k0p + (size_t)16 * (NKV_*HD_);
#pragma unroll
  for (int d0 = 0; d0 < HD_; d0 += 32) {
    int ka = d0 + quad * 8;
    bf16x8 a0 = *(const bf16x8*)(q0 + ka);
    bf16x8 a1 = *(const bf16x8*)(q1 + ka);
    bf16x8 b0f = *(const bf16x8*)(k0p + ka);
    bf16x8 b1f = *(const bf16x8*)(k1p + ka);
    acc[0][0] = MFMA(a0, b0f, acc[0][0]);
    acc[0][1] = MFMA(a0, b1f, acc[0][1]);
    acc[1][0] = MFMA(a1, b0f, acc[1][0]);
    acc[1][1] = MFMA(a1, b1f, acc[1][1]);
  }
#pragma unroll
  for (int i = 0; i < 2; ++i)
#pragma unroll
    for (int j = 0; j < 2; ++j) {
      int n = bk + wn + j*16 + l16;
#pragma unroll
      for (int r = 0; r < 4; ++r) {
        int m = bq + wm + i*16 + quad*4 + r;
        sc[((size_t)(zb*NH_ + h) * S_ + m) * SKV + n] =
            acc[i][j][r] + mask[((size_t)(b*S_ + m)) * SKV + n];
      }
    }
}

// ---------------- row softmax: fp32 scores in, bf16 P out (in place) ----------------
__global__ __launch_bounds__(256) void softmax_kernel(float* __restrict__ sc, int SKV, int nrows) {
  int row = blockIdx.x * 4 + (threadIdx.x >> 6);
  int lane = threadIdx.x & 63;
  if (row >= nrows) return;
  float* rp = sc + (size_t)row * SKV;
  short* sp = (short*)rp;
  float4 v[2];
  int nc = SKV >> 8;
  float mx = -1e30f;
#pragma unroll
  for (int c = 0; c < 2; ++c)
    if (c < nc) {
      v[c] = *(float4*)(rp + c*256 + lane*4);
      mx = fmaxf(mx, fmaxf(fmaxf(v[c].x, v[c].y), fmaxf(v[c].z, v[c].w)));
    }
#pragma unroll
  for (int m = 32; m > 0; m >>= 1) mx = fmaxf(mx, __shfl_xor(mx, m, 64));
  float ls = 0.f;
#pragma unroll
  for (int c = 0; c < 2; ++c)
    if (c < nc) {
      v[c].x = __expf(v[c].x - mx); v[c].y = __expf(v[c].y - mx);
      v[c].z = __expf(v[c].z - mx); v[c].w = __expf(v[c].w - mx);
      ls += v[c].x + v[c].y + v[c].z + v[c].w;
    }
#pragma unroll
  for (int m = 32; m > 0; m >>= 1) ls += __shfl_xor(ls, m, 64);
  float inv = 1.0f / ls;
#pragma unroll
  for (int c = 0; c < 2; ++c)
    if (c < nc) {
      s4 o;
      o.x = (short)f2b(v[c].x * inv); o.y = (short)f2b(v[c].y * inv);
      o.z = (short)f2b(v[c].z * inv); o.w = (short)f2b(v[c].w * inv);
      *(s4*)(sp + c*256 + lane*4) = o;
    }
}

// ---------------- P @ V -> attn out bf16 [b*S+q][h*64+d] ----------------
__global__ __launch_bounds__(256) void pv_mfma(const short* __restrict__ Pb,
                                               const short* __restrict__ vT,
                                               short* __restrict__ ob,
                                               int b0, int SKV) {
  int z = blockIdx.y, zb = z >> 4, h = z & 15, b = b0 + zb, kvh = h >> 2;
  int bq = blockIdx.x * 64;
  int lane = threadIdx.x & 63, wv = threadIdx.x >> 6;
  int wm = (wv & 1) * 32, wn = (wv >> 1) * 32;
  int quad = lane >> 4, l16 = lane & 15;
  f32x4 z4 = {0.f,0.f,0.f,0.f};
  f32x4 acc[2][2] = {{z4,z4},{z4,z4}};
  const short* p0 = Pb + ((size_t)(zb*NH_ + h) * S_ + bq + wm + l16) * (size_t)(2*SKV);
  const short* p1 = p0 + (size_t)16 * 2 * SKV;
  const short* v0 = vT + ((size_t)b * 256 + kvh*64 + wn + l16) * 512;
  const short* v1 = v0 + (size_t)16 * 512;
#pragma unroll 4
  for (int k0 = 0; k0 < SKV; k0 += 32) {
    int ka = k0 + quad * 8;
    bf16x8 a0 = *(const bf16x8*)(p0 + ka);
    bf16x8 a1 = *(const bf16x8*)(p1 + ka);
    bf16x8 b0f = *(const bf16x8*)(v0 + ka);
    bf16x8 b1f = *(const bf16x8*)(v1 + ka);
    acc[0][0] = MFMA(a0, b0f, acc[0][0]);
    acc[0][1] = MFMA(a0, b1f, acc[0][1]);
    acc[1][0] = MFMA(a1, b0f, acc[1][0]);
    acc[1][1] = MFMA(a1, b1f, acc[1][1]);
  }
#pragma unroll
  for (int i = 0; i < 2; ++i)
#pragma unroll
    for (int j = 0; j < 2; ++j) {
      int n = wn + j*16 + l16;
#pragma unroll
      for (int r = 0; r < 4; ++r) {
        int m = bq + wm + i*16 + quad*4 + r;
        ob[(size_t)(b*S_ + m) * D_ + h*HD_ + n] = (short)f2b(acc[i][j][r]);
      }
    }
}

// ---------------- MoE gate: H = bf16(gelu(x@W1e) * (x@W3e)) ----------------
__global__ __launch_bounds__(256) void moe_gate_mfma(const short* __restrict__ xlnb,
                                                     const float* __restrict__ W1,
                                                     const float* __restrict__ W3,
                                                     short* __restrict__ Hs,
                                                     const float* __restrict__ coef,
                                                     const int* __restrict__ slot) {
  int e = blockIdx.z;
  int bn = blockIdx.x * 64, bm = blockIdx.y * 64;
  int b = bm >> 8;
  if (coef[e * B_ + b] == 0.0f) return;
  int sl = slot[e * B_ + b];
  int lane = threadIdx.x & 63, wv = threadIdx.x >> 6;
  int wm = (wv & 1) * 32, wn = (wv >> 1) * 32;
  int quad = lane >> 4, l16 = lane & 15;
  f32x4 z4 = {0.f,0.f,0.f,0.f};
  f32x4 acc1[2][2] = {{z4,z4},{z4,z4}};
  f32x4 acc3[2][2] = {{z4,z4},{z4,z4}};
  const short* a0p = xlnb + (size_t)(bm + wm + l16) * D_;
  const short* a1p = a0p + (size_t)16 * D_;
  const float* w1p0 = W1 + (size_t)e * D_ * DE_ + bn + wn + l16;
  const float* w1p1 = w1p0 + 16;
  const float* w3p0 = W3 + (size_t)e * D_ * DE_ + bn + wn + l16;
  const float* w3p1 = w3p0 + 16;
#pragma unroll 2
  for (int k0 = 0; k0 < D_; k0 += 32) {
    int ka = k0 + quad * 8;
    bf16x8 a0 = *(const bf16x8*)(a0p + ka);
    bf16x8 a1 = *(const bf16x8*)(a1p + ka);
    bf16x8 b10 = load_w_frag(w1p0 + (size_t)ka * DE_, DE_);
    bf16x8 b11 = load_w_frag(w1p1 + (size_t)ka * DE_, DE_);
    bf16x8 b30 = load_w_frag(w3p0 + (size_t)ka * DE_, DE_);
    bf16x8 b31 = load_w_frag(w3p1 + (size_t)ka * DE_, DE_);
    acc1[0][0] = MFMA(a0, b10, acc1[0][0]);
    acc1[0][1] = MFMA(a0, b11, acc1[0][1]);
    acc1[1][0] = MFMA(a1, b10, acc1[1][0]);
    acc1[1][1] = MFMA(a1, b11, acc1[1][1]);
    acc3[0][0] = MFMA(a0, b30, acc3[0][0]);
    acc3[0][1] = MFMA(a0, b31, acc3[0][1]);
    acc3[1][0] = MFMA(a1, b30, acc3[1][0]);
    acc3[1][1] = MFMA(a1, b31, acc3[1][1]);
  }
  short* Hp = Hs + ((size_t)(sl * B_ + b) * S_ + (bm & 255)) * DE_;
#pragma unroll
  for (int i = 0; i < 2; ++i)
#pragma unroll
    for (int j = 0; j < 2; ++j) {
      int n = bn + wn + j*16 + l16;
#pragma unroll
      for (int r = 0; r < 4; ++r) {
        int lm = wm + i*16 + quad*4 + r;
        float c1 = acc1[i][j][r], c3 = acc3[i][j][r];
        float g = 0.5f * c1 * (1.0f + erff(c1 * 0.70710678118654752f));
        Hp[(size_t)lm * DE_ + n] = (short)f2b(g * c3);
      }
    }
}

// ---------------- MoE down: resid += coef * (H @ W2e), 4-way K-split ----------------
__global__ __launch_bounds__(256) void moe_down_mfma(const short* __restrict__ Hs,
                                                     const float* __restrict__ W2,
                                                     float* resid,
                                                     const float* __restrict__ coef,
                                                     const int* __restrict__ slot) {
  int zc = blockIdx.z;
  int e = zc >> 2, kc = zc & 3;
  int bn = blockIdx.x * 64, bm = blockIdx.y * 64;
  int b = bm >> 8;
  float cf = coef[e * B_ + b];
  if (cf == 0.0f) return;
  int sl = slot[e * B_ + b];
  int lane = threadIdx.x & 63, wv = threadIdx.x >> 6;
  int wm = (wv & 1) * 32, wn = (wv >> 1) * 32;
  int quad = lane >> 4, l16 = lane & 15;
  f32x4 z4 = {0.f,0.f,0.f,0.f};
  f32x4 acc[2][2] = {{z4,z4},{z4,z4}};
  const short* a0p = Hs + ((size_t)(sl * B_ + b) * S_ + (bm & 255) + wm + l16) * DE_ + kc * 1024;
  const short* a1p = a0p + (size_t)16 * DE_;
  const float* w0p = W2 + (size_t)e * DE_ * D_ + (size_t)kc * 1024 * D_ + bn + wn + l16;
  const float* w1p = w0p + 16;
#pragma unroll 2
  for (int k0 = 0; k0 < 1024; k0 += 32) {
    int ka = k0 + quad * 8;
    bf16x8 a0 = *(const bf16x8*)(a0p + ka);
    bf16x8 a1 = *(const bf16x8*)(a1p + ka);
    bf16x8 b0 = load_w_frag(w0p + (size_t)ka * D_, D_);
    bf16x8 b1 = load_w_frag(w1p + (size_t)ka * D_, D_);
    acc[0][0] = MFMA(a0, b0, acc[0][0]);
    acc[0][1] = MFMA(a0, b1, acc[0][1]);
    acc[1][0] = MFMA(a1, b0, acc[1][0]);
    acc[1][1] = MFMA(a1, b1, acc[1][1]);
  }
#pragma unroll
  for (int i = 0; i < 2; ++i)
#pragma unroll
    for (int j = 0; j < 2; ++j) {
      int n = bn + wn + j*16 + l16;
#pragma unroll
      for (int r = 0; r < 4; ++r) {
        int m = bm + wm + i*16 + quad*4 + r;
        atomicAdd(&resid[(size_t)m * D_ + n], cf * acc[i][j][r]);
      }
    }
}

// ---------------- MoE routing coefficients + slots ----------------
__global__ void coef_kernel(const int* __restrict__ langs, float* __restrict__ coef,
                            int* __restrict__ slot) {
  int t = threadIdx.x;
  if (t < NE_ * B_) {
    int e = t >> 2, b = t & 3;
    int l0 = langs[b*2], l1 = langs[b*2 + 1];
    int counts = (l0 > 3) + (l1 > 3);
    float rw = (counts == 0) ? 1.0f : 1.0f / (float)counts;
    bool m = (l0 == 4 + e) || (l1 == 4 + e);
    coef[t] = m ? rw : 0.0f;
    int s = 0;
    for (int ep = 0; ep < e; ++ep) s += ((l0 == 4 + ep) || (l1 == 4 + ep)) ? 1 : 0;
    slot[t] = s;
  }
}

extern "C" void kernel_launch(void* const* d_in, const int* in_sizes, int n_in,
                              void* d_out, int out_size, void* d_ws, size_t ws_size,
                              hipStream_t stream) {
  const float* hidden = (const float*)d_in[0];
  const float* enc    = (const float*)d_in[1];
  const float* amask  = (const float*)d_in[2];
  const float* emask  = (const float*)d_in[3];
  const int*   langs  = (const int*)d_in[4];
  const float* ln1g = (const float*)d_in[5];
  const float* ln1b = (const float*)d_in[6];
  const float* saqw = (const float*)d_in[7];
  const float* saqb = (const float*)d_in[8];
  const float* sakw = (const float*)d_in[9];
  const float* sakb = (const float*)d_in[10];
  const float* savw = (const float*)d_in[11];
  const float* savb = (const float*)d_in[12];
  const float* saow = (const float*)d_in[13];
  const float* saob = (const float*)d_in[14];
  const float* ln2g = (const float*)d_in[15];
  const float* ln2b = (const float*)d_in[16];
  const float* caqw = (const float*)d_in[17];
  const float* caqb = (const float*)d_in[18];
  const float* cakw = (const float*)d_in[19];
  const float* cakb = (const float*)d_in[20];
  const float* cavw = (const float*)d_in[21];
  const float* cavb = (const float*)d_in[22];
  const float* caow = (const float*)d_in[23];
  const float* caob = (const float*)d_in[24];
  const float* ln3g = (const float*)d_in[25];
  const float* ln3b = (const float*)d_in[26];
  const float* w1   = (const float*)d_in[27];
  const float* w2   = (const float*)d_in[28];
  const float* w3   = (const float*)d_in[29];

  float* resid = (float*)d_out;     // fp32 residual stream lives in d_out

  const int M = B_ * S_;            // 1024
  float* ws = (float*)d_ws;
  short* xlnb = (short*)ws;  ws += (M * D_) / 2;          //  512K fl
  short* encb = (short*)ws;  ws += (B_ * SK_ * D_) / 2;   // 1024K fl
  short* qb   = (short*)ws;  ws += (M * D_) / 2;          //  512K fl
  short* kb   = (short*)ws;  ws += (B_ * SK_ * 256) / 2;  //  256K fl
  short* vT   = (short*)ws;  ws += (B_ * 256 * 512) / 2;  //  256K fl
  short* ab   = (short*)ws;  ws += (M * D_) / 2;          //  512K fl
  float* scb  = ws;          ws += B_ * NH_ * S_ * S_;    // 4194K fl (scores / P / MoE-H alias)
  float* coef = ws;          ws += 32;
  int*   slot = (int*)ws;    ws += 32;                    // total ~29 MB
  short* Hs   = (short*)scb;                              // MoE hidden [2 slots][B][S][DE] bf16

  dim3 blk(256);

  // ---- self attention ----
  ln_kernel<<<M, blk, 0, stream>>>(hidden, ln1g, ln1b, xlnb);
  proj_mfma<<<dim3(16, 16), blk, 0, stream>>>(xlnb, saqw, saqb, qb, 0.125f, D_, D_);
  proj_mfma<<<dim3(4, 16), blk, 0, stream>>>(xlnb, sakw, sakb, kb, 1.0f, 256, D_);
  proj_v_mfma<<<dim3(4, 16), blk, 0, stream>>>(xlnb, savw, savb, vT, 256, D_);
  qk_mfma<<<dim3(4, 4, 4*NH_), blk, 0, stream>>>(qb, kb, amask, scb, 0, S_);
  softmax_kernel<<<(4*NH_*S_)/4, blk, 0, stream>>>(scb, S_, 4*NH_*S_);
  pv_mfma<<<dim3(4, 4*NH_), blk, 0, stream>>>((short*)scb, vT, ab, 0, S_);
  proj_o_mfma<<<dim3(16, 16), blk, 0, stream>>>(ab, saow, saob, hidden, resid, D_, D_);

  // ---- cross attention ----
  ln_kernel<<<M, blk, 0, stream>>>(resid, ln2g, ln2b, xlnb);
  proj_mfma<<<dim3(16, 16), blk, 0, stream>>>(xlnb, caqw, caqb, qb, 0.125f, D_, D_);
  cast_f2b<<<(B_*SK_*D_)/1024, blk, 0, stream>>>(enc, encb, B_*SK_*D_);
  proj_mfma<<<dim3(4, 32), blk, 0, stream>>>(encb, cakw, cakb, kb, 1.0f, 256, D_);
  proj_v_mfma<<<dim3(4, 32), blk, 0, stream>>>(encb, cavw, cavb, vT, 512, D_);
  for (int b0 = 0; b0 < B_; b0 += 2) {   // 2 batches/pass: fp32 scores fit scb
    qk_mfma<<<dim3(8, 4, 2*NH_), blk, 0, stream>>>(qb, kb, emask, scb, b0, SK_);
    softmax_kernel<<<(2*NH_*S_)/4, blk, 0, stream>>>(scb, SK_, 2*NH_*S_);
    pv_mfma<<<dim3(4, 2*NH_), blk, 0, stream>>>((short*)scb, vT, ab, b0, SK_);
  }
  proj_o_mfma<<<dim3(16, 16), blk, 0, stream>>>(ab, caow, caob, resid, resid, D_, D_);

  // ---- MoE ----
  ln_kernel<<<M, blk, 0, stream>>>(resid, ln3g, ln3b, xlnb);
  coef_kernel<<<1, 64, 0, stream>>>(langs, coef, slot);
  moe_gate_mfma<<<dim3(DE_/64, M/64, NE_), blk, 0, stream>>>(xlnb, w1, w3, Hs, coef, slot);
  moe_down_mfma<<<dim3(D_/64, M/64, NE_*4), blk, 0, stream>>>(Hs, w2, resid, coef, slot);
}